// Round 8
// baseline (508.159 us; speedup 1.0000x reference)
//
#include <hip/hip_runtime.h>
#include <cfloat>

typedef _Float16 half8  __attribute__((ext_vector_type(8)));
typedef float    floatx4 __attribute__((ext_vector_type(4)));
typedef int      intx4  __attribute__((ext_vector_type(4)));
typedef unsigned long long ull;

#define NBATCH 16
#define NSEQ   2048
#define ND     512
#define NC     8192
#define NTOK   (NBATCH * NSEQ)   // 32768
#define NTT    (NTOK / 128)      // 256 token tiles
#define NCT    (NC / 128)        // 64 code tiles
#define KQ     (ND / 64)         // 8 int8 K-steps (K=64 per MFMA)
#define SEGY   16                // rescore segment blocks (all segments concurrent)
// int8 approx: score err sigma ~0.033 (worst-row absmax~4.9); 0.35 = ~10 sigma.
#define MARGIN 0.35f

#define XSCALE 8.0f
#define ESCALE 64.0f
// exact rescore: acc = sum((8x)*(64e)) = 512*xy ; score = e2 - acc/256
#define SCORE_SCALE (2.0f / (XSCALE * ESCALE)) // 1/256

typedef const void __attribute__((address_space(1)))* gp_t;
typedef void       __attribute__((address_space(3)))* lp_t;
__device__ __forceinline__ void cp16(lp_t l, gp_t g) {
  // async global->LDS DMA, 16B/lane, LDS dst = wave-uniform base + lane*16
  __builtin_amdgcn_global_load_lds(g, l, 16, 0, 0);
}

// ---------------- prep: embed -> i8 qe + se + f16 split eh/el + e2 (+cnt=0) ------
__global__ __launch_bounds__(256) void prep_embed(const float* __restrict__ embed,
                                                  char* __restrict__ qe,
                                                  float* __restrict__ se,
                                                  _Float16* __restrict__ eh,
                                                  _Float16* __restrict__ el,
                                                  float* __restrict__ e2,
                                                  int* __restrict__ cnt) {
  if (blockIdx.x == 0 && threadIdx.x < NCT) cnt[threadIdx.x] = 0;
  int wave = threadIdx.x >> 6, lane = threadIdx.x & 63;
  int c = blockIdx.x * 4 + wave;
  const float* row = embed + (size_t)c * ND;
  float4 v0 = ((const float4*)row)[lane * 2];
  float4 v1 = ((const float4*)row)[lane * 2 + 1];
  float vs[8] = {v0.x, v0.y, v0.z, v0.w, v1.x, v1.y, v1.z, v1.w};
  float am = 0.f, s = 0.f;
#pragma unroll
  for (int q = 0; q < 8; ++q) { am = fmaxf(am, fabsf(vs[q])); s = fmaf(vs[q], vs[q], s); }
#pragma unroll
  for (int m = 1; m < 64; m <<= 1) {
    am = fmaxf(am, __shfl_xor(am, m, 64));
    s += __shfl_xor(s, m, 64);
  }
  float inv = am > 0.f ? 127.f / am : 0.f;
  ull pk = 0; half8 h, l;
#pragma unroll
  for (int q = 0; q < 8; ++q) {
    int qv = (int)rintf(vs[q] * inv);
    qv = min(127, max(-127, qv));
    pk |= (ull)(unsigned char)(signed char)qv << (8 * q);
    float sv = ESCALE * vs[q];
    _Float16 hh = (_Float16)sv;
    h[q] = hh;
    l[q] = (_Float16)(sv - (float)hh);
  }
  ((ull*)(qe + (size_t)c * ND))[lane] = pk;
  ((half8*)(eh + (size_t)c * ND))[lane] = h;
  ((half8*)(el + (size_t)c * ND))[lane] = l;
  if (lane == 0) { se[c] = am / 127.f; e2[c] = s; }
}

// ---------------- prep: x -> i8 qx + sx (+pKey init) ----------------
__global__ __launch_bounds__(256) void prep_xq(const float* __restrict__ x,
                                               char* __restrict__ qx,
                                               float* __restrict__ sx,
                                               unsigned long long* __restrict__ pKey) {
  int wave = threadIdx.x >> 6, lane = threadIdx.x & 63;
  int t = blockIdx.x * 4 + wave;
  const float* row = x + (size_t)t * ND;
  float4 v0 = ((const float4*)row)[lane * 2];
  float4 v1 = ((const float4*)row)[lane * 2 + 1];
  float vs[8] = {v0.x, v0.y, v0.z, v0.w, v1.x, v1.y, v1.z, v1.w};
  float am = 0.f;
#pragma unroll
  for (int q = 0; q < 8; ++q) am = fmaxf(am, fabsf(vs[q]));
#pragma unroll
  for (int m = 1; m < 64; m <<= 1) am = fmaxf(am, __shfl_xor(am, m, 64));
  float inv = am > 0.f ? 127.f / am : 0.f;
  ull pk = 0;
#pragma unroll
  for (int q = 0; q < 8; ++q) {
    int qv = (int)rintf(vs[q] * inv);
    qv = min(127, max(-127, qv));
    pk |= (ull)(unsigned char)(signed char)qv << (8 * q);
  }
  ((ull*)(qx + (size_t)t * ND))[lane] = pk;
  if (lane == 0) { sx[t] = am / 127.f; pKey[t] = ~0ULL; }
}

// ---------------- pass 1: i8 GEMM -> per-(token, code-tile) min ----------------
// R14: R13 with the block-invariant X stream moved OUT of the per-kt cadence.
// X tile -> registers once in the prologue (a[4][8], 128 VGPR; 32 dwordx4,
// 64B-line coalesced). The old LDS swizzle is self-inverse, so direct loads
// qx[row][kt*64+quad*16] give bitwise-identical A fragments (scores unchanged).
// Per kt now: 2 cp16 (E only) + 4 ds_read_b128 + 16 MFMA + 1 barrier -- half
// the DMA/LDS work per barrier. E ring-5 (40 KB); boundary vmcnt keeps 3
// E-tiles in flight (6/6/6/6/4/2/0). Prologue vmcnt(6) retires the 32 X loads
// (oldest) + tile0 while keeping tiles 1-3 in flight. launch_bounds(256,2)
// pins 2 waves/SIMD (2 blocks/CU preserved).
__global__ __launch_bounds__(256, 2) void vq_approx(
    const char* __restrict__ qx, const float* __restrict__ sx,
    const int* __restrict__ len,
    const char* __restrict__ qe, const float* __restrict__ se,
    const float* __restrict__ e2g,
    float* __restrict__ tMin) {
  __shared__ char sEb[5][128 * 64];   // 5 x 8 KiB E ring (40 KB)

  // 8x64 super-tiles: 512 consecutive blocks share 8 X-tiles (L2) + full qe
  const int gid = blockIdx.x;
  const int tt = (gid >> 9) * 8 + (gid & 7);
  const int ct = (gid & 511) >> 3;
  const int b = tt >> 4, s0 = (tt & 15) * 128;
  if (s0 >= len[b]) return;
  const int row0 = tt * 128, code0 = ct * 128;

  const int tid = threadIdx.x, wave = tid >> 6, lane = tid & 63;
  const int quad = lane >> 4, lid = lane & 15;
  const int wr = wave >> 1, wc = wave & 1;

  const int r0 = tid >> 2;
  const int csrc = (tid & 3) ^ ((tid >> 3) & 3);
  const int ldsb0 = wave * 1024;          // byte offsets
  const int ldsb1 = 4096 + wave * 1024;

  const int cswz = quad ^ ((lid >> 1) & 3);
  int boff[4];
#pragma unroll
  for (int j = 0; j < 4; ++j) boff[j] = (wc * 64 + j * 16 + lid) * 64 + cswz * 16;

  const char* peb = qe + (size_t)(code0 + r0) * ND + csrc * 16;

  // ---- X tile -> registers (issued FIRST: oldest VMEM ops, retired by the
  // prologue vmcnt(6) below). Fragment = qx[row][kt*64 + quad*16], bitwise
  // identical to the old swizzled-LDS read. ----
  const char* pa = qx + (size_t)(row0 + wr * 64 + lid) * ND + quad * 16;
  intx4 a[4][8];
#pragma unroll
  for (int i = 0; i < 4; ++i)
#pragma unroll
    for (int kt = 0; kt < 8; ++kt)
      a[i][kt] = *(const intx4*)(pa + i * 16 * ND + kt * 64);

  intx4 acc[4][4];
#pragma unroll
  for (int i = 0; i < 4; ++i)
#pragma unroll
    for (int j = 0; j < 4; ++j) acc[i][j] = (intx4){0, 0, 0, 0};

  // 2 VMEM issues per E tile per wave (8 KiB block-wide)
#define STAGE(bufi, kt) do { \
    cp16((lp_t)&sEb[bufi][ldsb0], (gp_t)(peb + (kt) * 64)); \
    cp16((lp_t)&sEb[bufi][ldsb1], (gp_t)(peb + 64 * ND + (kt) * 64)); } while (0)

  // prologue: stage E tiles 0..3 (8 issues); vmcnt(6) retires X loads + tile 0
  STAGE(0, 0);
  STAGE(1, 1);
  STAGE(2, 2);
  STAGE(3, 3);
  asm volatile("s_waitcnt vmcnt(6)" ::: "memory");
  __builtin_amdgcn_s_barrier();

#pragma unroll
  for (int kt = 0; kt < KQ; ++kt) {
    const int buf = kt % 5;
    // stage kt+4 into the buffer read at kt-1 (freed by the kt-1 barrier)
    if (kt + 4 < KQ) STAGE((kt + 4) % 5, kt + 4);
    const char* B = sEb[buf];
    intx4 bv[4];
#pragma unroll
    for (int j = 0; j < 4; ++j) bv[j] = *(const intx4*)&B[boff[j]];
    __builtin_amdgcn_s_setprio(1);
#pragma unroll
    for (int i = 0; i < 4; ++i)
#pragma unroll
      for (int j = 0; j < 4; ++j)
        acc[i][j] = __builtin_amdgcn_mfma_i32_16x16x64_i8(a[i][kt], bv[j], acc[i][j], 0, 0, 0);
    __builtin_amdgcn_s_setprio(0);
    // boundary: counted wait -- E tile kt+1 landed, up to 3 newer in flight
    if (kt < KQ - 1) {
      if (kt + 4 < KQ)      { asm volatile("s_waitcnt vmcnt(6)" ::: "memory"); }
      else if (kt + 3 < KQ) { asm volatile("s_waitcnt vmcnt(4)" ::: "memory"); }
      else if (kt + 2 < KQ) { asm volatile("s_waitcnt vmcnt(2)" ::: "memory"); }
      else                  { asm volatile("s_waitcnt vmcnt(0)" ::: "memory"); }
      __builtin_amdgcn_s_barrier();
    }
  }
#undef STAGE

  // per-token min over this 128-code tile: score = e2 - 2*sx*se*acc
  float e2v[4], sev[4];
#pragma unroll
  for (int j = 0; j < 4; ++j) {
    int col = code0 + wc * 64 + j * 16 + lid;
    e2v[j] = e2g[col];
    sev[j] = se[col];
  }
  float4 sx4[4];
#pragma unroll
  for (int i = 0; i < 4; ++i)
    sx4[i] = *(const float4*)&sx[row0 + wr * 64 + i * 16 + quad * 4];

  __syncthreads();                  // ring reads done -> alias LDS as scratch
  float* pm = (float*)&sEb[0][0];   // [128][33] padded: conflict-free reduce
#pragma unroll
  for (int i = 0; i < 4; ++i) {
#pragma unroll
    for (int reg = 0; reg < 4; ++reg) {
      const int row = wr * 64 + i * 16 + quad * 4 + reg;   // C/D row = quad*4+reg
      const float rs = 2.0f * sx4[i][reg];
      float best = fmaf(-rs * sev[0], (float)acc[i][0][reg], e2v[0]);
#pragma unroll
      for (int j = 1; j < 4; ++j)
        best = fminf(best, fmaf(-rs * sev[j], (float)acc[i][j][reg], e2v[j]));
      pm[row * 33 + wc * 16 + lid] = best;
    }
  }
  __syncthreads();
  if (tid < 128) {
    const float* r = pm + tid * 33;
    float mn = r[0];
#pragma unroll
    for (int k = 1; k < 32; ++k) mn = fminf(mn, r[k]);
    tMin[(size_t)(row0 + tid) * NCT + ct] = mn;
  }
}

// ---------------- pass 2: select candidate tiles per token ----------------
__global__ __launch_bounds__(256) void vq_select(
    const int* __restrict__ len, const float* __restrict__ tMin,
    int* __restrict__ list, int* __restrict__ cnt) {
  int wave = threadIdx.x >> 6, lane = threadIdx.x & 63;
  int t = blockIdx.x * 4 + wave;
  int b = t >> 11, s = t & (NSEQ - 1);
  if (s >= len[b]) return;   // wave-uniform
  float v = tMin[(size_t)t * NCT + lane];
  float m = v;
#pragma unroll
  for (int d = 1; d < 64; d <<= 1) m = fminf(m, __shfl_xor(m, d, 64));
  if (v <= m + MARGIN) {
    int pos = atomicAdd(&cnt[lane], 1);
    list[lane * NTOK + pos] = t;
  }
}

// ---------------- pass 3: exact 3-product f16 rescore (barrier-free, pipelined) ----
// One block per (code tile j, segment y). Each wave computes a 64x64 quadrant;
// A rows (gathered tokens) and B rows (codes) load global->register; kt loop
// unrolled x2 with ALL 32 loads of the pair issued before convert/MFMA.
// atomicMin on sortable (score,idx) u64 key: order-independent, idempotent.
__global__ __launch_bounds__(256, 1) void vq_rescore(
    const float* __restrict__ x,
    const _Float16* __restrict__ eh, const _Float16* __restrict__ el,
    const float* __restrict__ e2g,
    const int* __restrict__ list, const int* __restrict__ cnt,
    unsigned long long* __restrict__ pKey) {
  const int j = blockIdx.x;
  const int n = cnt[j];
  const int code0 = j * 128;
  if ((int)blockIdx.y * 128 >= n) return;

  const int tid = threadIdx.x, wave = tid >> 6, lane = tid & 63;
  const int quad = lane >> 4, lid = lane & 15;
  const int wr = wave >> 1, wc = wave & 1;

  float e2v[4]; int cjv[4];
#pragma unroll
  for (int jj = 0; jj < 4; ++jj) {
    cjv[jj] = code0 + wc * 64 + jj * 16 + lid;   // B row = C/D col = lane&15
    e2v[jj] = e2g[cjv[jj]];
  }

  for (int seg = blockIdx.y; seg * 128 < n; seg += SEGY) {
    const int base = seg * 128;
    int tok[4];
#pragma unroll
    for (int i = 0; i < 4; ++i)
      tok[i] = list[j * NTOK + min(base + wr * 64 + i * 16 + lid, n - 1)];

    floatx4 acc[4][4];
#pragma unroll
    for (int i = 0; i < 4; ++i)
#pragma unroll
      for (int jj = 0; jj < 4; ++jj) acc[i][jj] = (floatx4){0.f, 0.f, 0.f, 0.f};

    for (int kt = 0; kt < 16; kt += 2) {
      // ---- issue ALL loads for the kt pair (32 instrs in flight) ----
      float4 af[2][4][2];
#pragma unroll
      for (int s = 0; s < 2; ++s)
#pragma unroll
        for (int i = 0; i < 4; ++i) {
          const float* px = x + (size_t)tok[i] * ND + (kt + s) * 32 + quad * 8;
          af[s][i][0] = *(const float4*)px;
          af[s][i][1] = *(const float4*)(px + 4);
        }
      half8 bh[2][4], bl[2][4];
#pragma unroll
      for (int s = 0; s < 2; ++s)
#pragma unroll
        for (int jj = 0; jj < 4; ++jj) {
          const size_t eo = (size_t)cjv[jj] * ND + (kt + s) * 32 + quad * 8;
          bh[s][jj] = *(const half8*)(eh + eo);
          bl[s][jj] = *(const half8*)(el + eo);
        }
      // ---- process sub-steps in order (same arithmetic order as before) ----
#pragma unroll
      for (int s = 0; s < 2; ++s) {
        half8 ah[4], al[4];
#pragma unroll
        for (int i = 0; i < 4; ++i) {
          float vs[8] = {af[s][i][0].x, af[s][i][0].y, af[s][i][0].z, af[s][i][0].w,
                         af[s][i][1].x, af[s][i][1].y, af[s][i][1].z, af[s][i][1].w};
#pragma unroll
          for (int q = 0; q < 8; ++q) {
            float vv = XSCALE * vs[q];
            _Float16 hh = (_Float16)vv;
            ah[i][q] = hh;
            al[i][q] = (_Float16)(vv - (float)hh);
          }
        }
#pragma unroll
        for (int i = 0; i < 4; ++i)
#pragma unroll
          for (int jj = 0; jj < 4; ++jj) {
            acc[i][jj] = __builtin_amdgcn_mfma_f32_16x16x32_f16(ah[i], bh[s][jj], acc[i][jj], 0, 0, 0);
            acc[i][jj] = __builtin_amdgcn_mfma_f32_16x16x32_f16(ah[i], bl[s][jj], acc[i][jj], 0, 0, 0);
            acc[i][jj] = __builtin_amdgcn_mfma_f32_16x16x32_f16(al[i], bh[s][jj], acc[i][jj], 0, 0, 0);
          }
      }
    }

    // epilogue: per-row argmin over the 128 codes, publish via atomicMin
#pragma unroll
    for (int i = 0; i < 4; ++i) {
#pragma unroll
      for (int reg = 0; reg < 4; ++reg) {
        float best = fmaf(-SCORE_SCALE, acc[i][0][reg], e2v[0]);
        int bidx = cjv[0];
#pragma unroll
        for (int jj = 1; jj < 4; ++jj) {
          float vj = fmaf(-SCORE_SCALE, acc[i][jj][reg], e2v[jj]);
          if (vj < best) { best = vj; bidx = cjv[jj]; }   // strict <: lowest idx on ties
        }
#pragma unroll
        for (int m = 1; m < 16; m <<= 1) {
          float ov = __shfl_xor(best, m, 64);
          int   oi = __shfl_xor(bidx, m, 64);
          if (ov < best || (ov == best && oi < bidx)) { best = ov; bidx = oi; }
        }
        if (lid == 0) {
          int row = wr * 64 + i * 16 + quad * 4 + reg;    // C/D row = quad*4+reg
          int t = list[j * NTOK + min(base + row, n - 1)];
          if (best == 0.0f) best = 0.0f;                  // normalize -0
          unsigned u = __float_as_uint(best);
          u ^= (u >> 31) ? 0xFFFFFFFFu : 0x80000000u;     // sortable fp32
          unsigned long long key = ((unsigned long long)u << 32) | (unsigned)bidx;
          atomicMin(&pKey[t], key);
        }
      }
    }
  }
}

// ---------------- decode key, gather code row, apply mask ----------------
__global__ __launch_bounds__(256) void vq_output(
    const float* __restrict__ embed, const int* __restrict__ len,
    const unsigned long long* __restrict__ pKey,
    float* __restrict__ out) {
  int wave = threadIdx.x >> 6, lane = threadIdx.x & 63;
  int t = blockIdx.x * 4 + wave;
  int b = t >> 11, s = t & (NSEQ - 1);
  float* outq = out + (size_t)t * ND;
  float* outind = out + (size_t)NTOK * ND;
  if (s >= len[b]) {
    float4 z = {0.f, 0.f, 0.f, 0.f};
    *(float4*)&outq[lane * 8]     = z;
    *(float4*)&outq[lane * 8 + 4] = z;
    if (lane == 0) outind[t] = -1.0f;
    return;
  }
  unsigned long long key = pKey[t];
  int bi = (int)(unsigned)(key & 0xFFFFFFFFULL);
  const float* er = embed + (size_t)bi * ND;
  *(float4*)&outq[lane * 8]     = *(const float4*)&er[lane * 8];
  *(float4*)&outq[lane * 8 + 4] = *(const float4*)&er[lane * 8 + 4];
  if (lane == 0) outind[t] = (float)bi;
}

extern "C" void kernel_launch(void* const* d_in, const int* in_sizes, int n_in,
                              void* d_out, int out_size, void* d_ws, size_t ws_size,
                              hipStream_t stream) {
  const float* x     = (const float*)d_in[0];
  const int*   lenp  = (const int*)d_in[1];
  const float* embed = (const float*)d_in[2];
  float* out = (float*)d_out;

  // ws: qe 4M | se 32K | eh 8M | el 8M | e2 32K | qx 16M | sx 128K |
  //     tMin 8M | list 8M | cnt | pKey 256K   ~52.5 MB
  char* w = (char*)d_ws;
  size_t off = 0;
  char*     qe = (char*)(w + off);     off += (size_t)NC * ND;
  float*    se = (float*)(w + off);    off += (size_t)NC * 4;
  _Float16* eh = (_Float16*)(w + off); off += (size_t)NC * ND * 2;
  _Float16* el = (_Float16*)(w + off); off += (size_t)NC * ND * 2;
  float*    e2 = (float*)(w + off);    off += (size_t)NC * 4;
  char*     qx = (char*)(w + off);     off += (size_t)NTOK * ND;
  float*    sx = (float*)(w + off);    off += (size_t)NTOK * 4;
  float*  tMin = (float*)(w + off);    off += (size_t)NTOK * NCT * 4;
  int*    list = (int*)(w + off);      off += (size_t)NCT * NTOK * 4;
  int*     cnt = (int*)(w + off);      off += 256;
  unsigned long long* pKey = (unsigned long long*)(w + off); off += (size_t)NTOK * 8;

  prep_embed<<<NC / 4, 256, 0, stream>>>(embed, qe, se, eh, el, e2, cnt);
  prep_xq<<<NTOK / 4, 256, 0, stream>>>(x, qx, sx, pKey);
  vq_approx<<<NTT * NCT, 256, 0, stream>>>(qx, sx, lenp, qe, se, e2, tMin);
  vq_select<<<NTOK / 4, 256, 0, stream>>>(lenp, tMin, list, cnt);
  vq_rescore<<<dim3(NCT, SEGY), 256, 0, stream>>>(x, eh, el, e2, list, cnt, pKey);
  vq_output<<<NTOK / 4, 256, 0, stream>>>(embed, lenp, pKey, out);
}

// Round 9
// 506.352 us; speedup vs baseline: 1.0036x; 1.0036x over previous
//
#include <hip/hip_runtime.h>
#include <cfloat>

typedef _Float16 half8  __attribute__((ext_vector_type(8)));
typedef float    floatx4 __attribute__((ext_vector_type(4)));
typedef int      intx4  __attribute__((ext_vector_type(4)));
typedef unsigned long long ull;

#define NBATCH 16
#define NSEQ   2048
#define ND     512
#define NC     8192
#define NTOK   (NBATCH * NSEQ)   // 32768
#define NTT    (NTOK / 128)      // 256 token tiles
#define NCT    (NC / 128)        // 64 code tiles
#define KQ     (ND / 64)         // 8 int8 K-steps (K=64 per MFMA)
#define SEGY   16                // rescore segment blocks (all segments concurrent)
// int8 approx: score err sigma ~0.033 (worst-row absmax~4.9); 0.35 = ~10 sigma.
#define MARGIN 0.35f

#define XSCALE 8.0f
#define ESCALE 64.0f
// exact rescore: acc = sum((8x)*(64e)) = 512*xy ; score = e2 - acc/256
#define SCORE_SCALE (2.0f / (XSCALE * ESCALE)) // 1/256

typedef const void __attribute__((address_space(1)))* gp_t;
typedef void       __attribute__((address_space(3)))* lp_t;
__device__ __forceinline__ void cp16(lp_t l, gp_t g) {
  // async global->LDS DMA, 16B/lane, LDS dst = wave-uniform base + lane*16
  __builtin_amdgcn_global_load_lds(g, l, 16, 0, 0);
}

// ---------------- fused prep: embed part + x part (one dispatch) ----------------
// blockIdx < NC/4:   embed -> i8 qe + se + f16 split eh/el + e2 (+cnt=0)
// blockIdx >= NC/4:  x -> i8 qx + sx (+pKey init)
__global__ __launch_bounds__(256) void prep(const float* __restrict__ embed,
                                            const float* __restrict__ x,
                                            char* __restrict__ qe,
                                            float* __restrict__ se,
                                            _Float16* __restrict__ eh,
                                            _Float16* __restrict__ el,
                                            float* __restrict__ e2,
                                            int* __restrict__ cnt,
                                            char* __restrict__ qx,
                                            float* __restrict__ sx,
                                            unsigned long long* __restrict__ pKey) {
  int wave = threadIdx.x >> 6, lane = threadIdx.x & 63;
  if (blockIdx.x < NC / 4) {
    if (blockIdx.x == 0 && threadIdx.x < NCT) cnt[threadIdx.x] = 0;
    int c = blockIdx.x * 4 + wave;
    const float* row = embed + (size_t)c * ND;
    float4 v0 = ((const float4*)row)[lane * 2];
    float4 v1 = ((const float4*)row)[lane * 2 + 1];
    float vs[8] = {v0.x, v0.y, v0.z, v0.w, v1.x, v1.y, v1.z, v1.w};
    float am = 0.f, s = 0.f;
#pragma unroll
    for (int q = 0; q < 8; ++q) { am = fmaxf(am, fabsf(vs[q])); s = fmaf(vs[q], vs[q], s); }
#pragma unroll
    for (int m = 1; m < 64; m <<= 1) {
      am = fmaxf(am, __shfl_xor(am, m, 64));
      s += __shfl_xor(s, m, 64);
    }
    float inv = am > 0.f ? 127.f / am : 0.f;
    ull pk = 0; half8 h, l;
#pragma unroll
    for (int q = 0; q < 8; ++q) {
      int qv = (int)rintf(vs[q] * inv);
      qv = min(127, max(-127, qv));
      pk |= (ull)(unsigned char)(signed char)qv << (8 * q);
      float sv = ESCALE * vs[q];
      _Float16 hh = (_Float16)sv;
      h[q] = hh;
      l[q] = (_Float16)(sv - (float)hh);
    }
    ((ull*)(qe + (size_t)c * ND))[lane] = pk;
    ((half8*)(eh + (size_t)c * ND))[lane] = h;
    ((half8*)(el + (size_t)c * ND))[lane] = l;
    if (lane == 0) { se[c] = am / 127.f; e2[c] = s; }
  } else {
    int t = (blockIdx.x - NC / 4) * 4 + wave;
    const float* row = x + (size_t)t * ND;
    float4 v0 = ((const float4*)row)[lane * 2];
    float4 v1 = ((const float4*)row)[lane * 2 + 1];
    float vs[8] = {v0.x, v0.y, v0.z, v0.w, v1.x, v1.y, v1.z, v1.w};
    float am = 0.f;
#pragma unroll
    for (int q = 0; q < 8; ++q) am = fmaxf(am, fabsf(vs[q]));
#pragma unroll
    for (int m = 1; m < 64; m <<= 1) am = fmaxf(am, __shfl_xor(am, m, 64));
    float inv = am > 0.f ? 127.f / am : 0.f;
    ull pk = 0;
#pragma unroll
    for (int q = 0; q < 8; ++q) {
      int qv = (int)rintf(vs[q] * inv);
      qv = min(127, max(-127, qv));
      pk |= (ull)(unsigned char)(signed char)qv << (8 * q);
    }
    ((ull*)(qx + (size_t)t * ND))[lane] = pk;
    if (lane == 0) { sx[t] = am / 127.f; pKey[t] = ~0ULL; }
  }
}

// ---------------- pass 1: i8 GEMM -> per-(token, code-tile) min ----------------
// R15: R14's X-in-registers, with the register residency FORCED. R14 failed
// because the compiler sank the 32 X loads into the kt loop (VGPR=104 proved
// a[4][8] never materialized) -> per-kt global latency + broken vmcnt counts.
// Fix: keep-alive asm ("+v" operand per fragment) forces all 32 fragments
// materialized before the loop (compiler must emit loads + waits first), then
// an explicit vmcnt(0) drain makes the E-ring's counted-vmcnt self-contained.
// Fragment = qx[row][kt*64+quad*16], bitwise identical to the old swizzled-LDS
// read (stage/read swizzles cancel: quad^((lid>>1)&3)^((lid>>1)&3) = quad).
// Per kt: 2 cp16 (E only) + 4 ds_read_b128 + 16 MFMA + 1 barrier -- half the
// LDS traffic (the largest per-kt term) vs R13. E ring-5 (40 KB); boundary
// vmcnt 6/6/6/6/4/2/0 keeps 3 E-tiles in flight.
__global__ __launch_bounds__(256, 2) void vq_approx(
    const char* __restrict__ qx, const float* __restrict__ sx,
    const int* __restrict__ len,
    const char* __restrict__ qe, const float* __restrict__ se,
    const float* __restrict__ e2g,
    float* __restrict__ tMin) {
  __shared__ char sEb[5][128 * 64];   // 5 x 8 KiB E ring (40 KB)

  // 8x64 super-tiles: 512 consecutive blocks share 8 X-tiles (L2) + full qe
  const int gid = blockIdx.x;
  const int tt = (gid >> 9) * 8 + (gid & 7);
  const int ct = (gid & 511) >> 3;
  const int b = tt >> 4, s0 = (tt & 15) * 128;
  if (s0 >= len[b]) return;
  const int row0 = tt * 128, code0 = ct * 128;

  const int tid = threadIdx.x, wave = tid >> 6, lane = tid & 63;
  const int quad = lane >> 4, lid = lane & 15;
  const int wr = wave >> 1, wc = wave & 1;

  const int r0 = tid >> 2;
  const int csrc = (tid & 3) ^ ((tid >> 3) & 3);
  const int ldsb0 = wave * 1024;          // byte offsets
  const int ldsb1 = 4096 + wave * 1024;

  const int cswz = quad ^ ((lid >> 1) & 3);
  int boff[4];
#pragma unroll
  for (int j = 0; j < 4; ++j) boff[j] = (wc * 64 + j * 16 + lid) * 64 + cswz * 16;

  const char* peb = qe + (size_t)(code0 + r0) * ND + csrc * 16;

  // ---- X tile -> registers, FORCED resident. ----
  const char* pa = qx + (size_t)(row0 + wr * 64 + lid) * ND + quad * 16;
  intx4 a[4][8];
#pragma unroll
  for (int i = 0; i < 4; ++i)
#pragma unroll
    for (int kt = 0; kt < 8; ++kt)
      a[i][kt] = *(const intx4*)(pa + i * 16 * ND + kt * 64);
  // keep-alive: each fragment becomes a live asm operand -> loads + waits are
  // emitted here, values pinned in VGPRs (expect ~230-250 VGPR, cap 256).
#pragma unroll
  for (int i = 0; i < 4; ++i)
#pragma unroll
    for (int kt = 0; kt < 8; ++kt)
      asm volatile("" : "+v"(a[i][kt]));
  __builtin_amdgcn_sched_barrier(0);
  asm volatile("s_waitcnt vmcnt(0)" ::: "memory");  // X retired: E counting clean

  intx4 acc[4][4];
#pragma unroll
  for (int i = 0; i < 4; ++i)
#pragma unroll
    for (int j = 0; j < 4; ++j) acc[i][j] = (intx4){0, 0, 0, 0};

  // 2 VMEM issues per E tile per wave (8 KiB block-wide)
#define STAGE(bufi, kt) do { \
    cp16((lp_t)&sEb[bufi][ldsb0], (gp_t)(peb + (kt) * 64)); \
    cp16((lp_t)&sEb[bufi][ldsb1], (gp_t)(peb + 64 * ND + (kt) * 64)); } while (0)

  // prologue: stage E tiles 0..3 (8 issues); vmcnt(6) lands tile 0
  STAGE(0, 0);
  STAGE(1, 1);
  STAGE(2, 2);
  STAGE(3, 3);
  asm volatile("s_waitcnt vmcnt(6)" ::: "memory");
  __builtin_amdgcn_s_barrier();

#pragma unroll
  for (int kt = 0; kt < KQ; ++kt) {
    const int buf = kt % 5;
    // stage kt+4 into the buffer read at kt-1 (freed by the kt-1 barrier)
    if (kt + 4 < KQ) STAGE((kt + 4) % 5, kt + 4);
    const char* B = sEb[buf];
    intx4 bv[4];
#pragma unroll
    for (int j = 0; j < 4; ++j) bv[j] = *(const intx4*)&B[boff[j]];
    __builtin_amdgcn_s_setprio(1);
#pragma unroll
    for (int i = 0; i < 4; ++i)
#pragma unroll
      for (int j = 0; j < 4; ++j)
        acc[i][j] = __builtin_amdgcn_mfma_i32_16x16x64_i8(a[i][kt], bv[j], acc[i][j], 0, 0, 0);
    __builtin_amdgcn_s_setprio(0);
    // boundary: counted wait -- E tile kt+1 landed, up to 3 newer in flight
    if (kt < KQ - 1) {
      if (kt + 4 < KQ)      { asm volatile("s_waitcnt vmcnt(6)" ::: "memory"); }
      else if (kt + 3 < KQ) { asm volatile("s_waitcnt vmcnt(4)" ::: "memory"); }
      else if (kt + 2 < KQ) { asm volatile("s_waitcnt vmcnt(2)" ::: "memory"); }
      else                  { asm volatile("s_waitcnt vmcnt(0)" ::: "memory"); }
      __builtin_amdgcn_s_barrier();
    }
  }
#undef STAGE

  // per-token min over this 128-code tile: score = e2 - 2*sx*se*acc
  float e2v[4], sev[4];
#pragma unroll
  for (int j = 0; j < 4; ++j) {
    int col = code0 + wc * 64 + j * 16 + lid;
    e2v[j] = e2g[col];
    sev[j] = se[col];
  }
  float4 sx4[4];
#pragma unroll
  for (int i = 0; i < 4; ++i)
    sx4[i] = *(const float4*)&sx[row0 + wr * 64 + i * 16 + quad * 4];

  __syncthreads();                  // ring reads done -> alias LDS as scratch
  float* pm = (float*)&sEb[0][0];   // [128][33] padded: conflict-free reduce
#pragma unroll
  for (int i = 0; i < 4; ++i) {
#pragma unroll
    for (int reg = 0; reg < 4; ++reg) {
      const int row = wr * 64 + i * 16 + quad * 4 + reg;   // C/D row = quad*4+reg
      const float rs = 2.0f * sx4[i][reg];
      float best = fmaf(-rs * sev[0], (float)acc[i][0][reg], e2v[0]);
#pragma unroll
      for (int j = 1; j < 4; ++j)
        best = fminf(best, fmaf(-rs * sev[j], (float)acc[i][j][reg], e2v[j]));
      pm[row * 33 + wc * 16 + lid] = best;
    }
  }
  __syncthreads();
  if (tid < 128) {
    const float* r = pm + tid * 33;
    float mn = r[0];
#pragma unroll
    for (int k = 1; k < 32; ++k) mn = fminf(mn, r[k]);
    tMin[(size_t)(row0 + tid) * NCT + ct] = mn;
  }
}

// ---------------- pass 2: select candidate tiles per token ----------------
__global__ __launch_bounds__(256) void vq_select(
    const int* __restrict__ len, const float* __restrict__ tMin,
    int* __restrict__ list, int* __restrict__ cnt) {
  int wave = threadIdx.x >> 6, lane = threadIdx.x & 63;
  int t = blockIdx.x * 4 + wave;
  int b = t >> 11, s = t & (NSEQ - 1);
  if (s >= len[b]) return;   // wave-uniform
  float v = tMin[(size_t)t * NCT + lane];
  float m = v;
#pragma unroll
  for (int d = 1; d < 64; d <<= 1) m = fminf(m, __shfl_xor(m, d, 64));
  if (v <= m + MARGIN) {
    int pos = atomicAdd(&cnt[lane], 1);
    list[lane * NTOK + pos] = t;
  }
}

// ---------------- pass 3: exact 3-product f16 rescore (barrier-free, pipelined) ----
// One block per (code tile j, segment y). Each wave computes a 64x64 quadrant;
// A rows (gathered tokens) and B rows (codes) load global->register; kt loop
// unrolled x2 with ALL 32 loads of the pair issued before convert/MFMA.
// atomicMin on sortable (score,idx) u64 key: order-independent, idempotent.
__global__ __launch_bounds__(256, 1) void vq_rescore(
    const float* __restrict__ x,
    const _Float16* __restrict__ eh, const _Float16* __restrict__ el,
    const float* __restrict__ e2g,
    const int* __restrict__ list, const int* __restrict__ cnt,
    unsigned long long* __restrict__ pKey) {
  const int j = blockIdx.x;
  const int n = cnt[j];
  const int code0 = j * 128;
  if ((int)blockIdx.y * 128 >= n) return;

  const int tid = threadIdx.x, wave = tid >> 6, lane = tid & 63;
  const int quad = lane >> 4, lid = lane & 15;
  const int wr = wave >> 1, wc = wave & 1;

  float e2v[4]; int cjv[4];
#pragma unroll
  for (int jj = 0; jj < 4; ++jj) {
    cjv[jj] = code0 + wc * 64 + jj * 16 + lid;   // B row = C/D col = lane&15
    e2v[jj] = e2g[cjv[jj]];
  }

  for (int seg = blockIdx.y; seg * 128 < n; seg += SEGY) {
    const int base = seg * 128;
    int tok[4];
#pragma unroll
    for (int i = 0; i < 4; ++i)
      tok[i] = list[j * NTOK + min(base + wr * 64 + i * 16 + lid, n - 1)];

    floatx4 acc[4][4];
#pragma unroll
    for (int i = 0; i < 4; ++i)
#pragma unroll
      for (int jj = 0; jj < 4; ++jj) acc[i][jj] = (floatx4){0.f, 0.f, 0.f, 0.f};

    for (int kt = 0; kt < 16; kt += 2) {
      // ---- issue ALL loads for the kt pair (32 instrs in flight) ----
      float4 af[2][4][2];
#pragma unroll
      for (int s = 0; s < 2; ++s)
#pragma unroll
        for (int i = 0; i < 4; ++i) {
          const float* px = x + (size_t)tok[i] * ND + (kt + s) * 32 + quad * 8;
          af[s][i][0] = *(const float4*)px;
          af[s][i][1] = *(const float4*)(px + 4);
        }
      half8 bh[2][4], bl[2][4];
#pragma unroll
      for (int s = 0; s < 2; ++s)
#pragma unroll
        for (int jj = 0; jj < 4; ++jj) {
          const size_t eo = (size_t)cjv[jj] * ND + (kt + s) * 32 + quad * 8;
          bh[s][jj] = *(const half8*)(eh + eo);
          bl[s][jj] = *(const half8*)(el + eo);
        }
      // ---- process sub-steps in order (same arithmetic order as before) ----
#pragma unroll
      for (int s = 0; s < 2; ++s) {
        half8 ah[4], al[4];
#pragma unroll
        for (int i = 0; i < 4; ++i) {
          float vs[8] = {af[s][i][0].x, af[s][i][0].y, af[s][i][0].z, af[s][i][0].w,
                         af[s][i][1].x, af[s][i][1].y, af[s][i][1].z, af[s][i][1].w};
#pragma unroll
          for (int q = 0; q < 8; ++q) {
            float vv = XSCALE * vs[q];
            _Float16 hh = (_Float16)vv;
            ah[i][q] = hh;
            al[i][q] = (_Float16)(vv - (float)hh);
          }
        }
#pragma unroll
        for (int i = 0; i < 4; ++i)
#pragma unroll
          for (int jj = 0; jj < 4; ++jj) {
            acc[i][jj] = __builtin_amdgcn_mfma_f32_16x16x32_f16(ah[i], bh[s][jj], acc[i][jj], 0, 0, 0);
            acc[i][jj] = __builtin_amdgcn_mfma_f32_16x16x32_f16(ah[i], bl[s][jj], acc[i][jj], 0, 0, 0);
            acc[i][jj] = __builtin_amdgcn_mfma_f32_16x16x32_f16(al[i], bh[s][jj], acc[i][jj], 0, 0, 0);
          }
      }
    }

    // epilogue: per-row argmin over the 128 codes, publish via atomicMin
#pragma unroll
    for (int i = 0; i < 4; ++i) {
#pragma unroll
      for (int reg = 0; reg < 4; ++reg) {
        float best = fmaf(-SCORE_SCALE, acc[i][0][reg], e2v[0]);
        int bidx = cjv[0];
#pragma unroll
        for (int jj = 1; jj < 4; ++jj) {
          float vj = fmaf(-SCORE_SCALE, acc[i][jj][reg], e2v[jj]);
          if (vj < best) { best = vj; bidx = cjv[jj]; }   // strict <: lowest idx on ties
        }
#pragma unroll
        for (int m = 1; m < 16; m <<= 1) {
          float ov = __shfl_xor(best, m, 64);
          int   oi = __shfl_xor(bidx, m, 64);
          if (ov < best || (ov == best && oi < bidx)) { best = ov; bidx = oi; }
        }
        if (lid == 0) {
          int row = wr * 64 + i * 16 + quad * 4 + reg;    // C/D row = quad*4+reg
          int t = list[j * NTOK + min(base + row, n - 1)];
          if (best == 0.0f) best = 0.0f;                  // normalize -0
          unsigned u = __float_as_uint(best);
          u ^= (u >> 31) ? 0xFFFFFFFFu : 0x80000000u;     // sortable fp32
          unsigned long long key = ((unsigned long long)u << 32) | (unsigned)bidx;
          atomicMin(&pKey[t], key);
        }
      }
    }
  }
}

// ---------------- decode key, gather code row, apply mask ----------------
__global__ __launch_bounds__(256) void vq_output(
    const float* __restrict__ embed, const int* __restrict__ len,
    const unsigned long long* __restrict__ pKey,
    float* __restrict__ out) {
  int wave = threadIdx.x >> 6, lane = threadIdx.x & 63;
  int t = blockIdx.x * 4 + wave;
  int b = t >> 11, s = t & (NSEQ - 1);
  float* outq = out + (size_t)t * ND;
  float* outind = out + (size_t)NTOK * ND;
  if (s >= len[b]) {
    float4 z = {0.f, 0.f, 0.f, 0.f};
    *(float4*)&outq[lane * 8]     = z;
    *(float4*)&outq[lane * 8 + 4] = z;
    if (lane == 0) outind[t] = -1.0f;
    return;
  }
  unsigned long long key = pKey[t];
  int bi = (int)(unsigned)(key & 0xFFFFFFFFULL);
  const float* er = embed + (size_t)bi * ND;
  *(float4*)&outq[lane * 8]     = *(const float4*)&er[lane * 8];
  *(float4*)&outq[lane * 8 + 4] = *(const float4*)&er[lane * 8 + 4];
  if (lane == 0) outind[t] = (float)bi;
}

extern "C" void kernel_launch(void* const* d_in, const int* in_sizes, int n_in,
                              void* d_out, int out_size, void* d_ws, size_t ws_size,
                              hipStream_t stream) {
  const float* x     = (const float*)d_in[0];
  const int*   lenp  = (const int*)d_in[1];
  const float* embed = (const float*)d_in[2];
  float* out = (float*)d_out;

  // ws: qe 4M | se 32K | eh 8M | el 8M | e2 32K | qx 16M | sx 128K |
  //     tMin 8M | list 8M | cnt | pKey 256K   ~52.5 MB
  char* w = (char*)d_ws;
  size_t off = 0;
  char*     qe = (char*)(w + off);     off += (size_t)NC * ND;
  float*    se = (float*)(w + off);    off += (size_t)NC * 4;
  _Float16* eh = (_Float16*)(w + off); off += (size_t)NC * ND * 2;
  _Float16* el = (_Float16*)(w + off); off += (size_t)NC * ND * 2;
  float*    e2 = (float*)(w + off);    off += (size_t)NC * 4;
  char*     qx = (char*)(w + off);     off += (size_t)NTOK * ND;
  float*    sx = (float*)(w + off);    off += (size_t)NTOK * 4;
  float*  tMin = (float*)(w + off);    off += (size_t)NTOK * NCT * 4;
  int*    list = (int*)(w + off);      off += (size_t)NCT * NTOK * 4;
  int*     cnt = (int*)(w + off);      off += 256;
  unsigned long long* pKey = (unsigned long long*)(w + off); off += (size_t)NTOK * 8;

  prep<<<NC / 4 + NTOK / 4, 256, 0, stream>>>(embed, x, qe, se, eh, el, e2, cnt, qx, sx, pKey);
  vq_approx<<<NTT * NCT, 256, 0, stream>>>(qx, sx, lenp, qe, se, e2, tMin);
  vq_select<<<NTOK / 4, 256, 0, stream>>>(lenp, tMin, list, cnt);
  vq_rescore<<<dim3(NCT, SEGY), 256, 0, stream>>>(x, eh, el, e2, list, cnt, pKey);
  vq_output<<<NTOK / 4, 256, 0, stream>>>(embed, lenp, pKey, out);
}

// Round 10
// 396.903 us; speedup vs baseline: 1.2803x; 1.2758x over previous
//
#include <hip/hip_runtime.h>
#include <cfloat>

typedef _Float16 half8  __attribute__((ext_vector_type(8)));
typedef float    floatx4 __attribute__((ext_vector_type(4)));
typedef int      intx4  __attribute__((ext_vector_type(4)));
typedef unsigned long long ull;

#define NBATCH 16
#define NSEQ   2048
#define ND     512
#define NC     8192
#define NTOK   (NBATCH * NSEQ)   // 32768
#define NTT    (NTOK / 128)      // 256 token tiles
#define NCT    (NC / 128)        // 64 code tiles (tMin granularity)
#define NCB    (NC / 256)        // 32 approx block-columns
#define KQ     (ND / 64)         // 8 int8 K-steps (K=64 per MFMA)
#define SEGY   16                // rescore segment blocks (all segments concurrent)
// int8 approx: score err sigma ~0.033 (worst-row absmax~4.9); 0.35 = ~10 sigma.
#define MARGIN 0.35f

#define XSCALE 8.0f
#define ESCALE 64.0f
// exact rescore: acc = sum((8x)*(64e)) = 512*xy ; score = e2 - acc/256
#define SCORE_SCALE (2.0f / (XSCALE * ESCALE)) // 1/256

typedef const void __attribute__((address_space(1)))* gp_t;
typedef void       __attribute__((address_space(3)))* lp_t;
__device__ __forceinline__ void cp16(lp_t l, gp_t g) {
  // async global->LDS DMA, 16B/lane, LDS dst = wave-uniform base + lane*16
  __builtin_amdgcn_global_load_lds(g, l, 16, 0, 0);
}

// ---------------- fused prep: embed part + x part (one dispatch) ----------------
// blockIdx < NC/4:   embed -> i8 qe + se + f16 split eh/el + e2 (+cnt=0)
// blockIdx >= NC/4:  x -> i8 qx + sx (+pKey init)
__global__ __launch_bounds__(256) void prep(const float* __restrict__ embed,
                                            const float* __restrict__ x,
                                            char* __restrict__ qe,
                                            float* __restrict__ se,
                                            _Float16* __restrict__ eh,
                                            _Float16* __restrict__ el,
                                            float* __restrict__ e2,
                                            int* __restrict__ cnt,
                                            char* __restrict__ qx,
                                            float* __restrict__ sx,
                                            unsigned long long* __restrict__ pKey) {
  int wave = threadIdx.x >> 6, lane = threadIdx.x & 63;
  if (blockIdx.x < NC / 4) {
    if (blockIdx.x == 0 && threadIdx.x < NCT) cnt[threadIdx.x] = 0;
    int c = blockIdx.x * 4 + wave;
    const float* row = embed + (size_t)c * ND;
    float4 v0 = ((const float4*)row)[lane * 2];
    float4 v1 = ((const float4*)row)[lane * 2 + 1];
    float vs[8] = {v0.x, v0.y, v0.z, v0.w, v1.x, v1.y, v1.z, v1.w};
    float am = 0.f, s = 0.f;
#pragma unroll
    for (int q = 0; q < 8; ++q) { am = fmaxf(am, fabsf(vs[q])); s = fmaf(vs[q], vs[q], s); }
#pragma unroll
    for (int m = 1; m < 64; m <<= 1) {
      am = fmaxf(am, __shfl_xor(am, m, 64));
      s += __shfl_xor(s, m, 64);
    }
    float inv = am > 0.f ? 127.f / am : 0.f;
    ull pk = 0; half8 h, l;
#pragma unroll
    for (int q = 0; q < 8; ++q) {
      int qv = (int)rintf(vs[q] * inv);
      qv = min(127, max(-127, qv));
      pk |= (ull)(unsigned char)(signed char)qv << (8 * q);
      float sv = ESCALE * vs[q];
      _Float16 hh = (_Float16)sv;
      h[q] = hh;
      l[q] = (_Float16)(sv - (float)hh);
    }
    ((ull*)(qe + (size_t)c * ND))[lane] = pk;
    ((half8*)(eh + (size_t)c * ND))[lane] = h;
    ((half8*)(el + (size_t)c * ND))[lane] = l;
    if (lane == 0) { se[c] = am / 127.f; e2[c] = s; }
  } else {
    int t = (blockIdx.x - NC / 4) * 4 + wave;
    const float* row = x + (size_t)t * ND;
    float4 v0 = ((const float4*)row)[lane * 2];
    float4 v1 = ((const float4*)row)[lane * 2 + 1];
    float vs[8] = {v0.x, v0.y, v0.z, v0.w, v1.x, v1.y, v1.z, v1.w};
    float am = 0.f;
#pragma unroll
    for (int q = 0; q < 8; ++q) am = fmaxf(am, fabsf(vs[q]));
#pragma unroll
    for (int m = 1; m < 64; m <<= 1) am = fmaxf(am, __shfl_xor(am, m, 64));
    float inv = am > 0.f ? 127.f / am : 0.f;
    ull pk = 0;
#pragma unroll
    for (int q = 0; q < 8; ++q) {
      int qv = (int)rintf(vs[q] * inv);
      qv = min(127, max(-127, qv));
      pk |= (ull)(unsigned char)(signed char)qv << (8 * q);
    }
    ((ull*)(qx + (size_t)t * ND))[lane] = pk;
    if (lane == 0) { sx[t] = am / 127.f; pKey[t] = ~0ULL; }
  }
}

// ---------------- pass 1: i8 GEMM -> per-(token, code-tile) min ----------------
// R16: R13 structure (proven best) with the N-tile WIDENED: block = 128 tokens
// x 256 codes, 4 waves in 2x2 (each wave 64x128 = 32 MFMA/kt, 2x R13), same
// 1-barrier-per-kt cadence -- amortizes the measured ~2400 cyc/kt pacing over
// twice the work. Ring-3 of 24 KB (X 8K + E 16K) = 72 KB LDS -> 2 blocks/CU
// (the proven residency). Prefetch age 2 double-bodies == R12's winning age.
// Self-inverse swizzle unchanged (valid for any 16-multiple row base). Integer
// acc exact + min order-independent -> tMin identical, MARGIN semantics safe.
__global__ __launch_bounds__(256, 2) void vq_approx(
    const char* __restrict__ qx, const float* __restrict__ sx,
    const int* __restrict__ len,
    const char* __restrict__ qe, const float* __restrict__ se,
    const float* __restrict__ e2g,
    float* __restrict__ tMin) {
  __shared__ char sXb[3][128 * 64];   // 3 x 8 KiB X ring
  __shared__ char sEb[3][256 * 64];   // 3 x 16 KiB E ring

  // 8x32 super-tiles: 256 consecutive blocks share 8 X-tiles (L2) + full qe
  const int gid = blockIdx.x;
  const int tt = (gid >> 8) * 8 + (gid & 7);
  const int ct2 = (gid & 255) >> 3;        // 0..31, 256-code column
  const int b = tt >> 4, s0 = (tt & 15) * 128;
  if (s0 >= len[b]) return;
  const int row0 = tt * 128, code0 = ct2 * 256;

  const int tid = threadIdx.x, wave = tid >> 6, lane = tid & 63;
  const int quad = lane >> 4, lid = lane & 15;
  const int wr = wave >> 1, wc = wave & 1;   // 2x2 wave grid

  const int r0 = tid >> 2;
  const int csrc = (tid & 3) ^ ((tid >> 3) & 3);
  const int ldsw = wave * 1024;              // per-wave stage base (bytes)

  const int cswz = quad ^ ((lid >> 1) & 3);
  int aoff[4], boff[8];
#pragma unroll
  for (int i = 0; i < 4; ++i) aoff[i] = (wr * 64 + i * 16 + lid) * 64 + cswz * 16;
#pragma unroll
  for (int j = 0; j < 8; ++j) boff[j] = (wc * 128 + j * 16 + lid) * 64 + cswz * 16;

  const char* pxb = qx + (size_t)(row0 + r0) * ND + csrc * 16;
  const char* peb = qe + (size_t)(code0 + r0) * ND + csrc * 16;

  intx4 acc[4][8];
#pragma unroll
  for (int i = 0; i < 4; ++i)
#pragma unroll
    for (int j = 0; j < 8; ++j) acc[i][j] = (intx4){0, 0, 0, 0};

  // 6 VMEM issues per tile per wave (X 8 KiB + E 16 KiB block-wide per kt)
#define STAGE(bufi, kt) do { \
    cp16((lp_t)&sXb[bufi][ldsw],         (gp_t)(pxb + (kt) * 64)); \
    cp16((lp_t)&sXb[bufi][4096 + ldsw],  (gp_t)(pxb + 64 * ND + (kt) * 64)); \
    cp16((lp_t)&sEb[bufi][ldsw],         (gp_t)(peb + (kt) * 64)); \
    cp16((lp_t)&sEb[bufi][4096 + ldsw],  (gp_t)(peb + 64 * ND + (kt) * 64)); \
    cp16((lp_t)&sEb[bufi][8192 + ldsw],  (gp_t)(peb + 128 * ND + (kt) * 64)); \
    cp16((lp_t)&sEb[bufi][12288 + ldsw], (gp_t)(peb + 192 * ND + (kt) * 64)); } while (0)

  // prologue: stage tiles 0,1 (12 issues); land tile 0, keep tile 1 in flight
  STAGE(0, 0);
  STAGE(1, 1);
  asm volatile("s_waitcnt vmcnt(6)" ::: "memory");
  __builtin_amdgcn_s_barrier();

#pragma unroll
  for (int kt = 0; kt < KQ; ++kt) {
    const int buf = kt % 3;
    // stage kt+2 into the buffer read at kt-1 (freed by the kt-1 barrier)
    if (kt + 2 < KQ) STAGE((kt + 2) % 3, kt + 2);
    const char* A = sXb[buf];
    const char* B = sEb[buf];
    intx4 av[4], bv[8];
#pragma unroll
    for (int j = 0; j < 8; ++j) bv[j] = *(const intx4*)&B[boff[j]];
#pragma unroll
    for (int i = 0; i < 4; ++i) av[i] = *(const intx4*)&A[aoff[i]];
    __builtin_amdgcn_s_setprio(1);
#pragma unroll
    for (int i = 0; i < 4; ++i)
#pragma unroll
      for (int j = 0; j < 8; ++j)
        acc[i][j] = __builtin_amdgcn_mfma_i32_16x16x64_i8(av[i], bv[j], acc[i][j], 0, 0, 0);
    __builtin_amdgcn_s_setprio(0);
    // boundary: counted wait -- tile kt+1 landed, tile kt+2 stays in flight
    if (kt < KQ - 1) {
      if (kt + 2 < KQ) { asm volatile("s_waitcnt vmcnt(6)" ::: "memory"); }
      else             { asm volatile("s_waitcnt vmcnt(0)" ::: "memory"); }
      __builtin_amdgcn_s_barrier();
    }
  }
#undef STAGE

  // per-token min: wave's 128-col half == one tMin tile (ct2*2 + wc)
  float e2v[8], sev[8];
#pragma unroll
  for (int j = 0; j < 8; ++j) {
    int col = code0 + wc * 128 + j * 16 + lid;
    e2v[j] = e2g[col];
    sev[j] = se[col];
  }
  float4 sx4[4];
#pragma unroll
  for (int i = 0; i < 4; ++i)
    sx4[i] = *(const float4*)&sx[row0 + wr * 64 + i * 16 + quad * 4];

  __syncthreads();                  // ring reads done -> alias LDS as scratch
  float* pm = (float*)&sXb[0][0];   // [128][34]: row*34 + tile*17 + lid (2-way max)
#pragma unroll
  for (int i = 0; i < 4; ++i) {
#pragma unroll
    for (int reg = 0; reg < 4; ++reg) {
      const int row = wr * 64 + i * 16 + quad * 4 + reg;   // C/D row = quad*4+reg
      const float rs = 2.0f * sx4[i][reg];
      float best = fmaf(-rs * sev[0], (float)acc[i][0][reg], e2v[0]);
#pragma unroll
      for (int j = 1; j < 8; ++j)
        best = fminf(best, fmaf(-rs * sev[j], (float)acc[i][j][reg], e2v[j]));
      pm[row * 34 + wc * 17 + lid] = best;
    }
  }
  __syncthreads();
  {
    const int row = tid >> 1, tile = tid & 1;
    const float* r = pm + row * 34 + tile * 17;
    float mn = r[0];
#pragma unroll
    for (int k = 1; k < 16; ++k) mn = fminf(mn, r[k]);
    tMin[(size_t)(row0 + row) * NCT + ct2 * 2 + tile] = mn;
  }
}

// ---------------- pass 2: select candidate tiles per token ----------------
__global__ __launch_bounds__(256) void vq_select(
    const int* __restrict__ len, const float* __restrict__ tMin,
    int* __restrict__ list, int* __restrict__ cnt) {
  int wave = threadIdx.x >> 6, lane = threadIdx.x & 63;
  int t = blockIdx.x * 4 + wave;
  int b = t >> 11, s = t & (NSEQ - 1);
  if (s >= len[b]) return;   // wave-uniform
  float v = tMin[(size_t)t * NCT + lane];
  float m = v;
#pragma unroll
  for (int d = 1; d < 64; d <<= 1) m = fminf(m, __shfl_xor(m, d, 64));
  if (v <= m + MARGIN) {
    int pos = atomicAdd(&cnt[lane], 1);
    list[lane * NTOK + pos] = t;
  }
}

// ---------------- pass 3: exact 3-product f16 rescore (barrier-free, pipelined) ----
// One block per (code tile j, segment y). Each wave computes a 64x64 quadrant;
// A rows (gathered tokens) and B rows (codes) load global->register; kt loop
// unrolled x2 with ALL 32 loads of the pair issued before convert/MFMA.
// atomicMin on sortable (score,idx) u64 key: order-independent, idempotent.
__global__ __launch_bounds__(256, 1) void vq_rescore(
    const float* __restrict__ x,
    const _Float16* __restrict__ eh, const _Float16* __restrict__ el,
    const float* __restrict__ e2g,
    const int* __restrict__ list, const int* __restrict__ cnt,
    unsigned long long* __restrict__ pKey) {
  const int j = blockIdx.x;
  const int n = cnt[j];
  const int code0 = j * 128;
  if ((int)blockIdx.y * 128 >= n) return;

  const int tid = threadIdx.x, wave = tid >> 6, lane = tid & 63;
  const int quad = lane >> 4, lid = lane & 15;
  const int wr = wave >> 1, wc = wave & 1;

  float e2v[4]; int cjv[4];
#pragma unroll
  for (int jj = 0; jj < 4; ++jj) {
    cjv[jj] = code0 + wc * 64 + jj * 16 + lid;   // B row = C/D col = lane&15
    e2v[jj] = e2g[cjv[jj]];
  }

  for (int seg = blockIdx.y; seg * 128 < n; seg += SEGY) {
    const int base = seg * 128;
    int tok[4];
#pragma unroll
    for (int i = 0; i < 4; ++i)
      tok[i] = list[j * NTOK + min(base + wr * 64 + i * 16 + lid, n - 1)];

    floatx4 acc[4][4];
#pragma unroll
    for (int i = 0; i < 4; ++i)
#pragma unroll
      for (int jj = 0; jj < 4; ++jj) acc[i][jj] = (floatx4){0.f, 0.f, 0.f, 0.f};

    for (int kt = 0; kt < 16; kt += 2) {
      // ---- issue ALL loads for the kt pair (32 instrs in flight) ----
      float4 af[2][4][2];
#pragma unroll
      for (int s = 0; s < 2; ++s)
#pragma unroll
        for (int i = 0; i < 4; ++i) {
          const float* px = x + (size_t)tok[i] * ND + (kt + s) * 32 + quad * 8;
          af[s][i][0] = *(const float4*)px;
          af[s][i][1] = *(const float4*)(px + 4);
        }
      half8 bh[2][4], bl[2][4];
#pragma unroll
      for (int s = 0; s < 2; ++s)
#pragma unroll
        for (int jj = 0; jj < 4; ++jj) {
          const size_t eo = (size_t)cjv[jj] * ND + (kt + s) * 32 + quad * 8;
          bh[s][jj] = *(const half8*)(eh + eo);
          bl[s][jj] = *(const half8*)(el + eo);
        }
      // ---- process sub-steps in order (same arithmetic order as before) ----
#pragma unroll
      for (int s = 0; s < 2; ++s) {
        half8 ah[4], al[4];
#pragma unroll
        for (int i = 0; i < 4; ++i) {
          float vs[8] = {af[s][i][0].x, af[s][i][0].y, af[s][i][0].z, af[s][i][0].w,
                         af[s][i][1].x, af[s][i][1].y, af[s][i][1].z, af[s][i][1].w};
#pragma unroll
          for (int q = 0; q < 8; ++q) {
            float vv = XSCALE * vs[q];
            _Float16 hh = (_Float16)vv;
            ah[i][q] = hh;
            al[i][q] = (_Float16)(vv - (float)hh);
          }
        }
#pragma unroll
        for (int i = 0; i < 4; ++i)
#pragma unroll
          for (int jj = 0; jj < 4; ++jj) {
            acc[i][jj] = __builtin_amdgcn_mfma_f32_16x16x32_f16(ah[i], bh[s][jj], acc[i][jj], 0, 0, 0);
            acc[i][jj] = __builtin_amdgcn_mfma_f32_16x16x32_f16(ah[i], bl[s][jj], acc[i][jj], 0, 0, 0);
            acc[i][jj] = __builtin_amdgcn_mfma_f32_16x16x32_f16(al[i], bh[s][jj], acc[i][jj], 0, 0, 0);
          }
      }
    }

    // epilogue: per-row argmin over the 128 codes, publish via atomicMin
#pragma unroll
    for (int i = 0; i < 4; ++i) {
#pragma unroll
      for (int reg = 0; reg < 4; ++reg) {
        float best = fmaf(-SCORE_SCALE, acc[i][0][reg], e2v[0]);
        int bidx = cjv[0];
#pragma unroll
        for (int jj = 1; jj < 4; ++jj) {
          float vj = fmaf(-SCORE_SCALE, acc[i][jj][reg], e2v[jj]);
          if (vj < best) { best = vj; bidx = cjv[jj]; }   // strict <: lowest idx on ties
        }
#pragma unroll
        for (int m = 1; m < 16; m <<= 1) {
          float ov = __shfl_xor(best, m, 64);
          int   oi = __shfl_xor(bidx, m, 64);
          if (ov < best || (ov == best && oi < bidx)) { best = ov; bidx = oi; }
        }
        if (lid == 0) {
          int row = wr * 64 + i * 16 + quad * 4 + reg;    // C/D row = quad*4+reg
          int t = list[j * NTOK + min(base + row, n - 1)];
          if (best == 0.0f) best = 0.0f;                  // normalize -0
          unsigned u = __float_as_uint(best);
          u ^= (u >> 31) ? 0xFFFFFFFFu : 0x80000000u;     // sortable fp32
          unsigned long long key = ((unsigned long long)u << 32) | (unsigned)bidx;
          atomicMin(&pKey[t], key);
        }
      }
    }
  }
}

// ---------------- decode key, gather code row, apply mask ----------------
__global__ __launch_bounds__(256) void vq_output(
    const float* __restrict__ embed, const int* __restrict__ len,
    const unsigned long long* __restrict__ pKey,
    float* __restrict__ out) {
  int wave = threadIdx.x >> 6, lane = threadIdx.x & 63;
  int t = blockIdx.x * 4 + wave;
  int b = t >> 11, s = t & (NSEQ - 1);
  float* outq = out + (size_t)t * ND;
  float* outind = out + (size_t)NTOK * ND;
  if (s >= len[b]) {
    float4 z = {0.f, 0.f, 0.f, 0.f};
    *(float4*)&outq[lane * 8]     = z;
    *(float4*)&outq[lane * 8 + 4] = z;
    if (lane == 0) outind[t] = -1.0f;
    return;
  }
  unsigned long long key = pKey[t];
  int bi = (int)(unsigned)(key & 0xFFFFFFFFULL);
  const float* er = embed + (size_t)bi * ND;
  *(float4*)&outq[lane * 8]     = *(const float4*)&er[lane * 8];
  *(float4*)&outq[lane * 8 + 4] = *(const float4*)&er[lane * 8 + 4];
  if (lane == 0) outind[t] = (float)bi;
}

extern "C" void kernel_launch(void* const* d_in, const int* in_sizes, int n_in,
                              void* d_out, int out_size, void* d_ws, size_t ws_size,
                              hipStream_t stream) {
  const float* x     = (const float*)d_in[0];
  const int*   lenp  = (const int*)d_in[1];
  const float* embed = (const float*)d_in[2];
  float* out = (float*)d_out;

  // ws: qe 4M | se 32K | eh 8M | el 8M | e2 32K | qx 16M | sx 128K |
  //     tMin 8M | list 8M | cnt | pKey 256K   ~52.5 MB
  char* w = (char*)d_ws;
  size_t off = 0;
  char*     qe = (char*)(w + off);     off += (size_t)NC * ND;
  float*    se = (float*)(w + off);    off += (size_t)NC * 4;
  _Float16* eh = (_Float16*)(w + off); off += (size_t)NC * ND * 2;
  _Float16* el = (_Float16*)(w + off); off += (size_t)NC * ND * 2;
  float*    e2 = (float*)(w + off);    off += (size_t)NC * 4;
  char*     qx = (char*)(w + off);     off += (size_t)NTOK * ND;
  float*    sx = (float*)(w + off);    off += (size_t)NTOK * 4;
  float*  tMin = (float*)(w + off);    off += (size_t)NTOK * NCT * 4;
  int*    list = (int*)(w + off);      off += (size_t)NCT * NTOK * 4;
  int*     cnt = (int*)(w + off);      off += 256;
  unsigned long long* pKey = (unsigned long long*)(w + off); off += (size_t)NTOK * 8;

  prep<<<NC / 4 + NTOK / 4, 256, 0, stream>>>(embed, x, qe, se, eh, el, e2, cnt, qx, sx, pKey);
  vq_approx<<<NTT * NCB, 256, 0, stream>>>(qx, sx, lenp, qe, se, e2, tMin);
  vq_select<<<NTOK / 4, 256, 0, stream>>>(lenp, tMin, list, cnt);
  vq_rescore<<<dim3(NCT, SEGY), 256, 0, stream>>>(x, eh, el, e2, list, cnt, pKey);
  vq_output<<<NTOK / 4, 256, 0, stream>>>(embed, lenp, pKey, out);
}